// Round 2
// baseline (1739.688 us; speedup 1.0000x reference)
//
#include <hip/hip_runtime.h>

// ---------------------------------------------------------------------------
// 3-kernel pipeline:
//  prep_weights: fp32->bf16 + K-permute; w_stem extended with w_vproj (K=1056)
//  conv_stem  : conv1(2x2s2)+conv2(3x3)+conv3(3x3), 32 samp/wg, B-frags in regs,
//               writes conv3 activations bf16 [B][1024] to ws (+2MiB offset)
//  stem_gru   : stem GEMM (M=64,K=1056 dbuf LDS) + GRU + fc, 64 samp/wg
// ---------------------------------------------------------------------------

typedef short bf8 __attribute__((ext_vector_type(8)));   // 8 x bf16 (4 VGPR)
typedef float f4  __attribute__((ext_vector_type(4)));   // MFMA C/D

#define MFMA(a, b, c) __builtin_amdgcn_mfma_f32_16x16x32_bf16(a, b, c, 0, 0, 0)

#define W2_OFF    0
#define W3_OFF    18432
#define WSTEM_OFF 92160          // [192][1056]
#define WIH_OFF   294912        // [576][192]
#define WHH_OFF   405504
#define W_TOTAL   516096
#define C3_OFF    (1 << 20)      // shorts (2 MiB bytes); conv3out [65536][1024]

__device__ __forceinline__ unsigned short f2bf(float f) {
    unsigned int u = __float_as_uint(f);
    u += 0x7fffu + ((u >> 16) & 1u);          // RNE
    return (unsigned short)(u >> 16);
}
__device__ __forceinline__ float bf2f(unsigned short h) {
    return __uint_as_float(((unsigned int)h) << 16);
}
__device__ __forceinline__ float lrelu(float v) { return v > 0.f ? v : 0.05f * v; }
__device__ __forceinline__ float sigm(float x) { return 1.f / (1.f + __expf(-x)); }
__device__ __forceinline__ float tanh_(float x) {
    float e = __expf(2.f * x);
    return 1.f - 2.f / (e + 1.f);
}
__device__ __forceinline__ int swzC(int q, int s) {
    return q ^ ((s & 3) << 3) ^ ((q >> 1) & 32);
}

// ---- weight prep ----------------------------------------------------------
__global__ void prep_weights(const float* __restrict__ w2, const float* __restrict__ w3,
                             const float* __restrict__ wstem, const float* __restrict__ wvp,
                             const float* __restrict__ wih, const float* __restrict__ whh,
                             unsigned short* __restrict__ o) {
    int i = blockIdx.x * 256 + threadIdx.x;
    if (i >= W_TOTAL) return;
    float val;
    if (i < W3_OFF) {
        int n = i / 288, k = i - n * 288;
        val = w2[n * 288 + (k & 31) * 9 + (k >> 5)];
    } else if (i < WSTEM_OFF) {
        int d = i - W3_OFF;
        int n = d / 576, k = d - n * 576;
        val = w3[n * 576 + (k & 63) * 9 + (k >> 6)];
    } else if (i < WIH_OFF) {
        int d = i - WSTEM_OFF;
        int n = d / 1056, k = d - n * 1056;
        if (k < 1024)       val = wstem[(n << 10) + (k & 127) * 8 + (k >> 7)];
        else if (k < 1033)  val = wvp[n * 9 + (k - 1024)];
        else                val = 0.f;
    } else if (i < WHH_OFF) {
        val = wih[i - WIH_OFF];
    } else {
        val = whh[i - WHH_OFF];
    }
    o[i] = f2bf(val);
}

// ---- K1: conv pipeline ----------------------------------------------------
// 2048 wgs x 256 thr, 32 samples/wg, chunks of 4.
// LDS: C1=[0,6144) 4x1536 | C2=[6144,12288) 4x1536
__global__ __launch_bounds__(256, 2) void conv_stem(
    const float* __restrict__ x, const float* __restrict__ w1,
    const unsigned short* __restrict__ ws, unsigned short* __restrict__ c3out)
{
    __shared__ __align__(16) unsigned short lds[12288];
    const int tid = threadIdx.x;
    const int wave = tid >> 6, lane = tid & 63;
    const int col = lane & 15, quad = lane >> 4;
    const int S0 = blockIdx.x * 32;

    // hoisted B fragments (loaded once per wg)
    bf8 Bf2[9];
    int kq2[9];
    #pragma unroll
    for (int ks = 0; ks < 9; ++ks) {
        int k0 = ks * 32 + quad * 8;
        Bf2[ks] = *(const bf8*)(ws + (wave * 16 + col) * 288 + k0);
        int ky = k0 / 96, r = k0 - 96 * ky;
        kq2[ks] = (ky * 8 + (r >> 5)) * 32 + (r & 31);
    }
    bf8 Bf3[2][18];
    int kq3[18];
    #pragma unroll
    for (int ks = 0; ks < 18; ++ks) {
        int k0 = ks * 32 + quad * 8;
        int ky = k0 / 192, r = k0 - 192 * ky;
        kq3[ks] = (ky * 6 + (r >> 6)) * 64 + (r & 63);
        Bf3[0][ks] = *(const bf8*)(ws + W3_OFF + ((wave * 2 + 0) * 16 + col) * 576 + k0);
        Bf3[1][ks] = *(const bf8*)(ws + W3_OFF + ((wave * 2 + 1) * 16 + col) * 576 + k0);
    }

    for (int c = 0; c < 8; ++c) {
        // ---- conv1 (co rotated by p to spread LDS banks)
        if (tid < 192) {
            int s = tid / 48, p = tid - s * 48;
            int y = p >> 3, xx = p & 7;
            const float* xp = x + (S0 + c * 4 + s) * 192 + y * 32 + xx * 2;
            float x00 = xp[0], x01 = xp[1], x10 = xp[16], x11 = xp[17];
            int base = s * 1536, sw = (s & 3) << 3;
            #pragma unroll
            for (int cc = 0; cc < 32; ++cc) {
                int co = (cc + p) & 31;
                float a = x00 * w1[co * 4] + x01 * w1[co * 4 + 1]
                        + x10 * w1[co * 4 + 2] + x11 * w1[co * 4 + 3];
                lds[base + ((p * 32 + co) ^ sw)] = f2bf(lrelu(a));
            }
        }
        __syncthreads();

        // ---- conv2: M=96, N=64 (wave n-tile), K=288
        {
            int n0 = wave * 16;
            #pragma unroll
            for (int mt2 = 0; mt2 < 3; ++mt2) {
                int m0 = mt2 * 32 + col, m1 = m0 + 16;
                int s0 = m0 & 3, p0 = m0 >> 2;
                int s1 = m1 & 3, p1 = m1 >> 2;
                int oy0 = p0 / 6, ox0 = p0 - 6 * oy0;
                int oy1 = p1 / 6, ox1 = p1 - 6 * oy1;
                int b0 = s0 * 1536, qb0 = (oy0 * 8 + ox0) * 32, sw0 = (s0 & 3) << 3;
                int b1 = s1 * 1536, qb1 = (oy1 * 8 + ox1) * 32, sw1 = (s1 & 3) << 3;
                f4 acc0 = {0.f, 0.f, 0.f, 0.f}, acc1 = {0.f, 0.f, 0.f, 0.f};
                #pragma unroll
                for (int ks = 0; ks < 9; ++ks) {
                    bf8 a0 = *(const bf8*)&lds[b0 + ((qb0 + kq2[ks]) ^ sw0)];
                    bf8 a1 = *(const bf8*)&lds[b1 + ((qb1 + kq2[ks]) ^ sw1)];
                    acc0 = MFMA(a0, Bf2[ks], acc0);
                    acc1 = MFMA(a1, Bf2[ks], acc1);
                }
                #pragma unroll
                for (int r = 0; r < 4; ++r) {
                    int m = mt2 * 32 + quad * 4 + r;
                    int s = m & 3, pos = m >> 2;
                    int q = pos * 64 + n0 + col;
                    lds[6144 + s * 1536 + swzC(q, s)] = f2bf(lrelu(acc0[r]));
                    m += 16; s = m & 3; pos = m >> 2;
                    q = pos * 64 + n0 + col;
                    lds[6144 + s * 1536 + swzC(q, s)] = f2bf(lrelu(acc1[r]));
                }
            }
        }
        __syncthreads();

        // ---- conv3: M=32, N=128 (wave->2 n-tiles), K=576 -> global
        {
            int m0 = col, m1 = 16 + col;
            int s0 = m0 & 3, p0 = m0 >> 2;
            int s1 = m1 & 3, p1 = m1 >> 2;
            int qb0 = ((p0 >> 2) * 6 + (p0 & 3)) * 64;
            int qb1 = ((p1 >> 2) * 6 + (p1 & 3)) * 64;
            int b0 = 6144 + s0 * 1536, b1 = 6144 + s1 * 1536;
            #pragma unroll
            for (int ntl = 0; ntl < 2; ++ntl) {
                int n0 = (wave * 2 + ntl) * 16;
                f4 acc0 = {0.f, 0.f, 0.f, 0.f}, acc1 = {0.f, 0.f, 0.f, 0.f};
                #pragma unroll
                for (int ks = 0; ks < 18; ++ks) {
                    bf8 a0 = *(const bf8*)&lds[b0 + swzC(qb0 + kq3[ks], s0)];
                    bf8 a1 = *(const bf8*)&lds[b1 + swzC(qb1 + kq3[ks], s1)];
                    acc0 = MFMA(a0, Bf3[ntl][ks], acc0);
                    acc1 = MFMA(a1, Bf3[ntl][ks], acc1);
                }
                #pragma unroll
                for (int r = 0; r < 4; ++r) {
                    int m = quad * 4 + r;
                    int s = m & 3, pos = m >> 2;
                    c3out[(S0 + c * 4 + s) * 1024 + pos * 128 + n0 + col] = f2bf(lrelu(acc0[r]));
                    m += 16; s = m & 3; pos = m >> 2;
                    c3out[(S0 + c * 4 + s) * 1024 + pos * 128 + n0 + col] = f2bf(lrelu(acc1[r]));
                }
            }
        }
        __syncthreads();
    }
}

// ---- K2: stem GEMM + GRU + fc --------------------------------------------
// 1024 wgs x 256 thr, M=64 samples/wg.
// LDS: FUSED=[0,12288) [64][192] swz | ASTG=[12288,28672) 2x[64][128] swz
//      phase B: HX=[12288,24576) [64][192] swz; LRL overwrites FUSED.
__global__ __launch_bounds__(256, 2) void stem_gru(
    const unsigned short* __restrict__ ws, const float* __restrict__ v,
    const float* __restrict__ hx, const float* __restrict__ bvp,
    const float* __restrict__ bih, const float* __restrict__ bhh,
    const float* __restrict__ wfc, float* __restrict__ out)
{
    __shared__ __align__(16) unsigned short lds[28672];
    const int tid = threadIdx.x;
    const int wave = tid >> 6, lane = tid & 63;
    const int col = lane & 15, quad = lane >> 4;
    const int S0 = blockIdx.x * 64;
    const unsigned short* c3 = ws + C3_OFF;
    const unsigned short* wstem = ws + WSTEM_OFF;

    // ============ phase A: stem GEMM, K=1056 (v_proj fused as K-tail) ======
    f4 acc[4][3];
    #pragma unroll
    for (int mt = 0; mt < 4; ++mt)
        #pragma unroll
        for (int t = 0; t < 3; ++t) acc[mt][t] = (f4){0.f, 0.f, 0.f, 0.f};

    const int sm = tid >> 2, sq = tid & 3;              // staging row/quarter
    const unsigned short* asrc = c3 + (S0 + sm) * 1024 + sq * 32;

    // stage chunk 0
    {
        #pragma unroll
        for (int i = 0; i < 4; ++i) {
            bf8 d = *(const bf8*)(asrc + i * 8);
            int gp = (sq * 4 + i) ^ (sm & 15);
            *(bf8*)&lds[12288 + sm * 128 + gp * 8] = d;
        }
    }
    __syncthreads();

    for (int kc = 0; kc < 8; ++kc) {
        bf8 nx[4];
        if (kc < 7) {
            const unsigned short* s2 = asrc + (kc + 1) * 128;
            #pragma unroll
            for (int i = 0; i < 4; ++i) nx[i] = *(const bf8*)(s2 + i * 8);
        }
        int abase = 12288 + (kc & 1) * 8192;
        #pragma unroll
        for (int ks = 0; ks < 4; ++ks) {
            int kl = ks * 32 + quad * 8;
            int kk = kc * 128 + kl;
            bf8 b0 = *(const bf8*)(wstem + (wave * 48 + col) * 1056 + kk);
            bf8 b1 = *(const bf8*)(wstem + (wave * 48 + 16 + col) * 1056 + kk);
            bf8 b2 = *(const bf8*)(wstem + (wave * 48 + 32 + col) * 1056 + kk);
            #pragma unroll
            for (int mt = 0; mt < 4; ++mt) {
                int m = mt * 16 + col;
                bf8 a = *(const bf8*)&lds[abase + m * 128 + (kl ^ ((m & 15) << 3))];
                acc[mt][0] = MFMA(a, b0, acc[mt][0]);
                acc[mt][1] = MFMA(a, b1, acc[mt][1]);
                acc[mt][2] = MFMA(a, b2, acc[mt][2]);
            }
        }
        if (kc < 7) {
            int wb = 12288 + ((kc + 1) & 1) * 8192;
            #pragma unroll
            for (int i = 0; i < 4; ++i) {
                int gp = (sq * 4 + i) ^ (sm & 15);
                *(bf8*)&lds[wb + sm * 128 + gp * 8] = nx[i];
            }
        }
        __syncthreads();
    }

    // K-tail: v (9 cols) into buf0
    if (tid < 64) {
        int m = tid;
        const float* vp = v + (S0 + m) * 9;
        __align__(16) unsigned short tmp[32];
        #pragma unroll
        for (int i = 0; i < 9; ++i) tmp[i] = f2bf(vp[i]);
        #pragma unroll
        for (int i = 9; i < 32; ++i) tmp[i] = 0;
        #pragma unroll
        for (int g = 0; g < 4; ++g) {
            int gp = g ^ (m & 15);
            *(bf8*)&lds[12288 + m * 128 + gp * 8] = *(bf8*)&tmp[g * 8];
        }
    }
    __syncthreads();
    {
        int kl = quad * 8;                               // 0..31
        bf8 b0 = *(const bf8*)(wstem + (wave * 48 + col) * 1056 + 1024 + kl);
        bf8 b1 = *(const bf8*)(wstem + (wave * 48 + 16 + col) * 1056 + 1024 + kl);
        bf8 b2 = *(const bf8*)(wstem + (wave * 48 + 32 + col) * 1056 + 1024 + kl);
        #pragma unroll
        for (int mt = 0; mt < 4; ++mt) {
            int m = mt * 16 + col;
            bf8 a = *(const bf8*)&lds[12288 + m * 128 + (kl ^ ((m & 15) << 3))];
            acc[mt][0] = MFMA(a, b0, acc[mt][0]);
            acc[mt][1] = MFMA(a, b1, acc[mt][1]);
            acc[mt][2] = MFMA(a, b2, acc[mt][2]);
        }
    }

    // epilogue: + bias, lrelu -> FUSED
    #pragma unroll
    for (int t = 0; t < 3; ++t) {
        int n = wave * 48 + t * 16 + col;
        float bb = bvp[n];
        #pragma unroll
        for (int mt = 0; mt < 4; ++mt)
            #pragma unroll
            for (int r = 0; r < 4; ++r) {
                int m = mt * 16 + quad * 4 + r;
                lds[m * 192 + (n ^ ((m & 7) << 3))] = f2bf(lrelu(acc[mt][t][r] + bb));
            }
    }
    __syncthreads();

    // ============ phase B: GRU ============================================
    // stage hx bf16 -> [12288,24576)
    {
        int m = tid >> 2, qq = tid & 3;
        const float* hp = hx + (S0 + m) * 192 + qq * 48;
        #pragma unroll
        for (int i = 0; i < 6; ++i) {
            f4 d = *(const f4*)(hp + i * 8 + 0);
            f4 d2 = *(const f4*)(hp + i * 8 + 4);
            __align__(16) unsigned short tmp[8];
            #pragma unroll
            for (int u = 0; u < 4; ++u) { tmp[u] = f2bf(d[u]); tmp[4 + u] = f2bf(d2[u]); }
            int g = qq * 6 + i, gp = g ^ (m & 7);
            *(bf8*)&lds[12288 + m * 192 + gp * 8] = *(bf8*)tmp;
        }
    }
    __syncthreads();

    float lrlbuf[3][4][4];
    #pragma unroll
    for (int t = 0; t < 3; ++t) {
        int j0 = (wave * 3 + t) * 16;
        int j = j0 + col;
        const unsigned short* pih = ws + WIH_OFF + j * 192;
        const unsigned short* phh = ws + WHH_OFF + j * 192;
        f4 g0[4], g1[4], g2[4], g3[4], g4[4], g5[4];
        #pragma unroll
        for (int mt = 0; mt < 4; ++mt) {
            g0[mt] = (f4){0.f,0.f,0.f,0.f}; g1[mt] = g0[mt]; g2[mt] = g0[mt];
            g3[mt] = g0[mt]; g4[mt] = g0[mt]; g5[mt] = g0[mt];
        }
        #pragma unroll
        for (int ks = 0; ks < 6; ++ks) {
            int k0 = ks * 32 + quad * 8;
            bf8 bir = *(const bf8*)(pih + k0);
            bf8 bhr = *(const bf8*)(phh + k0);
            bf8 biz = *(const bf8*)(pih + 36864 + k0);
            bf8 bhz = *(const bf8*)(phh + 36864 + k0);
            bf8 bin = *(const bf8*)(pih + 73728 + k0);
            bf8 bhn = *(const bf8*)(phh + 73728 + k0);
            #pragma unroll
            for (int mt = 0; mt < 4; ++mt) {
                int m = mt * 16 + col;
                int off = m * 192 + (k0 ^ ((m & 7) << 3));
                bf8 aF = *(const bf8*)&lds[off];
                bf8 aH = *(const bf8*)&lds[12288 + off];
                g0[mt] = MFMA(aF, bir, g0[mt]);
                g1[mt] = MFMA(aH, bhr, g1[mt]);
                g2[mt] = MFMA(aF, biz, g2[mt]);
                g3[mt] = MFMA(aH, bhz, g3[mt]);
                g4[mt] = MFMA(aF, bin, g4[mt]);
                g5[mt] = MFMA(aH, bhn, g5[mt]);
            }
        }
        float b_ir = bih[j], b_iz = bih[192 + j], b_in = bih[384 + j];
        float b_hr = bhh[j], b_hz = bhh[192 + j], b_hn = bhh[384 + j];
        #pragma unroll
        for (int mt = 0; mt < 4; ++mt)
            #pragma unroll
            for (int r = 0; r < 4; ++r) {
                int s = mt * 16 + quad * 4 + r;
                float rg = sigm(g0[mt][r] + b_ir + g1[mt][r] + b_hr);
                float zg = sigm(g2[mt][r] + b_iz + g3[mt][r] + b_hz);
                float ng = tanh_(g4[mt][r] + b_in + rg * (g5[mt][r] + b_hn));
                float hxv = hx[(S0 + s) * 192 + j];
                float hnew = (1.f - zg) * ng + zg * hxv;
                out[65536 * 4 + (S0 + s) * 192 + j] = hnew;
                lrlbuf[t][mt][r] = lrelu(hnew);
            }
    }
    __syncthreads();   // all FUSED/HX reads done

    // write lrelu(hx') into FUSED region for fc
    #pragma unroll
    for (int t = 0; t < 3; ++t) {
        int j = (wave * 3 + t) * 16 + col;
        #pragma unroll
        for (int mt = 0; mt < 4; ++mt)
            #pragma unroll
            for (int r = 0; r < 4; ++r) {
                int m = mt * 16 + quad * 4 + r;
                lds[m * 192 + (j ^ ((m & 7) << 3))] = f2bf(lrlbuf[t][mt][r]);
            }
    }
    __syncthreads();

    // fc head: one thread per (sample, act)
    {
        int s = tid >> 2, a = tid & 3;
        const float* wf = wfc + a * 192;
        float sum = 0.f;
        #pragma unroll
        for (int g = 0; g < 24; ++g) {
            bf8 av = *(const bf8*)&lds[s * 192 + ((g ^ (s & 7)) << 3)];
            #pragma unroll
            for (int i = 0; i < 8; ++i)
                sum += bf2f((unsigned short)av[i]) * wf[g * 8 + i];
        }
        out[(S0 + s) * 4 + a] = sum;
    }
}

// ---------------------------------------------------------------------------
extern "C" void kernel_launch(void* const* d_in, const int* in_sizes, int n_in,
                              void* d_out, int out_size, void* d_ws, size_t ws_size,
                              hipStream_t stream) {
    const float* x     = (const float*)d_in[0];
    const float* v     = (const float*)d_in[1];
    const float* hx    = (const float*)d_in[2];
    const float* w1    = (const float*)d_in[3];
    const float* w2    = (const float*)d_in[4];
    const float* w3    = (const float*)d_in[5];
    const float* wstem = (const float*)d_in[6];
    const float* wvp   = (const float*)d_in[7];
    const float* bvp   = (const float*)d_in[8];
    const float* wih   = (const float*)d_in[9];
    const float* whh   = (const float*)d_in[10];
    const float* bih   = (const float*)d_in[11];
    const float* bhh   = (const float*)d_in[12];
    const float* wfc   = (const float*)d_in[13];
    unsigned short* wsp = (unsigned short*)d_ws;

    prep_weights<<<2016, 256, 0, stream>>>(w2, w3, wstem, wvp, wih, whh, wsp);
    conv_stem<<<2048, 256, 0, stream>>>(x, w1, wsp, wsp + C3_OFF);
    stem_gru<<<1024, 256, 0, stream>>>(wsp, v, hx, bvp, bih, bhh, wfc, (float*)d_out);
}

// Round 3
// 581.743 us; speedup vs baseline: 2.9905x; 2.9905x over previous
//
#include <hip/hip_runtime.h>

// ---------------------------------------------------------------------------
// 4-stage pipeline (B processed in quarters to bound ws usage ~187 MB):
//  prep_weights: fp32->bf16 + K-permute; w_stem extended with w_vproj (K=1056)
//  conv12 : conv1(2x2s2)+conv2(3x3); Bf2 (36 VGPR) resident; writes conv2 out
//           bf16 [16384][24][64] PRE-SWIZZLED for conv3k's LDS reads
//  conv3k : GEMM M=Bq*8,N=128(half/wg),K=576; Bf3 72 VGPR; writes c3out
//           bf16 [B][1024] PRE-SWIZZLED (key s&15) for stem_gru
//  stem_gru: stem GEMM (M=64,K=1056) + GRU + fc
// All kernels designed < ~120 arch VGPRs (R2 spill post-mortem).
// ---------------------------------------------------------------------------

typedef short bf8 __attribute__((ext_vector_type(8)));   // 8 x bf16
typedef float f4  __attribute__((ext_vector_type(4)));   // MFMA C/D

#define MFMA(a, b, c) __builtin_amdgcn_mfma_f32_16x16x32_bf16(a, b, c, 0, 0, 0)

#define W3_OFF    18432
#define WSTEM_OFF 92160          // [192][1056]
#define WIH_OFF   294912         // [576][192]
#define WHH_OFF   405504
#define W_TOTAL   516096
#define C3_OFF    (1 << 20)      // shorts; c3out [65536][1024]
#define C2Q_OFF   68157440       // shorts; c2 quarter [16384][24][64]

__device__ __forceinline__ unsigned short f2bf(float f) {
    unsigned int u = __float_as_uint(f);
    u += 0x7fffu + ((u >> 16) & 1u);          // RNE
    return (unsigned short)(u >> 16);
}
__device__ __forceinline__ float bf2f(unsigned short h) {
    return __uint_as_float(((unsigned int)h) << 16);
}
__device__ __forceinline__ float lrelu(float v) { return v > 0.f ? v : 0.05f * v; }
__device__ __forceinline__ float sigm(float x) { return 1.f / (1.f + __expf(-x)); }
__device__ __forceinline__ float tanh_(float x) {
    float e = __expf(2.f * x);
    return 1.f - 2.f / (e + 1.f);
}

// ---- weight prep ----------------------------------------------------------
__global__ void prep_weights(const float* __restrict__ w2, const float* __restrict__ w3,
                             const float* __restrict__ wstem, const float* __restrict__ wvp,
                             const float* __restrict__ wih, const float* __restrict__ whh,
                             unsigned short* __restrict__ o) {
    int i = blockIdx.x * 256 + threadIdx.x;
    if (i >= W_TOTAL) return;
    float val;
    if (i < W3_OFF) {
        int n = i / 288, k = i - n * 288;
        val = w2[n * 288 + (k & 31) * 9 + (k >> 5)];
    } else if (i < WSTEM_OFF) {
        int d = i - W3_OFF;
        int n = d / 576, k = d - n * 576;
        val = w3[n * 576 + (k & 63) * 9 + (k >> 6)];
    } else if (i < WIH_OFF) {
        int d = i - WSTEM_OFF;
        int n = d / 1056, k = d - n * 1056;
        if (k < 1024)       val = wstem[(n << 10) + (k & 127) * 8 + (k >> 7)];
        else if (k < 1033)  val = wvp[n * 9 + (k - 1024)];
        else                val = 0.f;
    } else if (i < WHH_OFF) {
        val = wih[i - WIH_OFF];
    } else {
        val = whh[i - WHH_OFF];
    }
    o[i] = f2bf(val);
}

// ---- K1: conv1 + conv2 ----------------------------------------------------
// 512 wgs/quarter, 32 samples/wg, chunks of 4. LDS: C1 only (12 KB).
__global__ __launch_bounds__(256, 2) void conv12(
    const float* __restrict__ x, const float* __restrict__ w1,
    const unsigned short* __restrict__ ws, unsigned short* __restrict__ c2q,
    int sbase)
{
    __shared__ __align__(16) unsigned short lds[6144];
    const int tid = threadIdx.x;
    const int wave = tid >> 6, lane = tid & 63;
    const int col = lane & 15, quad = lane >> 4;
    const int W0 = blockIdx.x * 32;                 // quarter-local sample base

    bf8 Bf2[9];
    int kq2[9];
    #pragma unroll
    for (int ks = 0; ks < 9; ++ks) {
        int k0 = ks * 32 + quad * 8;
        Bf2[ks] = *(const bf8*)(ws + (wave * 16 + col) * 288 + k0);
        int ky = k0 / 96, r = k0 - 96 * ky;
        kq2[ks] = (ky * 8 + (r >> 5)) * 32 + (r & 31);
    }
    const int g = wave * 2 + (col >> 3);            // c2 store ch-group

    for (int c = 0; c < 8; ++c) {
        // conv1: 2x2 s2, 1->32ch -> C1 [s][p48][co32] swizzled
        if (tid < 192) {
            int s = tid / 48, p = tid - s * 48;
            int y = p >> 3, xx = p & 7;
            const float* xp = x + (size_t)(sbase + W0 + c * 4 + s) * 192 + y * 32 + xx * 2;
            float x00 = xp[0], x01 = xp[1], x10 = xp[16], x11 = xp[17];
            int base = s * 1536, sw = (s & 3) << 3;
            #pragma unroll
            for (int cc = 0; cc < 32; ++cc) {
                int co = (cc + p) & 31;
                float a = x00 * w1[co * 4] + x01 * w1[co * 4 + 1]
                        + x10 * w1[co * 4 + 2] + x11 * w1[co * 4 + 3];
                lds[base + ((p * 32 + co) ^ sw)] = f2bf(lrelu(a));
            }
        }
        __syncthreads();

        // conv2: M=96 (m=pos*4+s), N=64 (wave n-tile), K=288 -> global c2q
        #pragma unroll
        for (int mt2 = 0; mt2 < 3; ++mt2) {
            int m0 = mt2 * 32 + col, m1 = m0 + 16;
            int s0 = m0 & 3, p0 = m0 >> 2;
            int s1 = m1 & 3, p1 = m1 >> 2;
            int oy0 = p0 / 6, ox0 = p0 - 6 * oy0;
            int oy1 = p1 / 6, ox1 = p1 - 6 * oy1;
            int b0 = s0 * 1536, qb0 = (oy0 * 8 + ox0) * 32, sw0 = (s0 & 3) << 3;
            int b1 = s1 * 1536, qb1 = (oy1 * 8 + ox1) * 32, sw1 = (s1 & 3) << 3;
            f4 acc0 = {0.f, 0.f, 0.f, 0.f}, acc1 = {0.f, 0.f, 0.f, 0.f};
            #pragma unroll
            for (int ks = 0; ks < 9; ++ks) {
                bf8 a0 = *(const bf8*)&lds[b0 + ((qb0 + kq2[ks]) ^ sw0)];
                bf8 a1 = *(const bf8*)&lds[b1 + ((qb1 + kq2[ks]) ^ sw1)];
                acc0 = MFMA(a0, Bf2[ks], acc0);
                acc1 = MFMA(a1, Bf2[ks], acc1);
            }
            #pragma unroll
            for (int r = 0; r < 4; ++r) {
                int m = mt2 * 32 + quad * 4 + r;
                int s = m & 3, pos = m >> 2;
                int sloc = W0 + c * 4 + s;
                int key = (pos + ((sloc & 1) << 2)) & 7;
                c2q[(size_t)sloc * 1536 + pos * 64 + ((g ^ key) << 3) + (col & 7)]
                    = f2bf(lrelu(acc0[r]));
                m += 16; s = m & 3; pos = m >> 2;
                sloc = W0 + c * 4 + s;
                key = (pos + ((sloc & 1) << 2)) & 7;
                c2q[(size_t)sloc * 1536 + pos * 64 + ((g ^ key) << 3) + (col & 7)]
                    = f2bf(lrelu(acc1[r]));
            }
        }
        __syncthreads();
    }
}

// ---- K2: conv3 as GEMM ----------------------------------------------------
// 512 wgs/quarter: sblk=bid>>1 (64 samples), h=bid&1 (N-half).
// Bf3 72 VGPR/wave; A staged 8 samples (24 KB LDS) per chunk, verbatim copy.
__global__ __launch_bounds__(256, 2) void conv3k(
    const unsigned short* __restrict__ ws, const unsigned short* __restrict__ c2q,
    unsigned short* __restrict__ c3, int sbase)
{
    __shared__ __align__(16) unsigned short lds[12288];
    const int tid = threadIdx.x;
    const int wave = tid >> 6, lane = tid & 63;
    const int col = lane & 15, quad = lane >> 4;
    const int h = blockIdx.x & 1;
    const int Q0 = (blockIdx.x >> 1) * 64;          // quarter-local base
    const int n_in = h * 64 + wave * 16 + col;      // out channel 0..127

    bf8 Bf3[18];
    #pragma unroll
    for (int ks = 0; ks < 18; ++ks)
        Bf3[ks] = *(const bf8*)(ws + W3_OFF + n_in * 576 + ks * 32 + quad * 8);

    // lane-const A offsets (element units), matching K1's baked swizzle
    int aoff[18];
    {
        int opos = col & 7;
        int oy = opos >> 2, ox = opos & 3;
        int spar = (col >> 3) & 1;
        #pragma unroll
        for (int ks = 0; ks < 18; ++ks) {
            int k0 = ks * 32 + quad * 8;
            int b = k0 >> 6;
            int ky = b / 3, kx = b - 3 * ky;
            int pos2 = (oy + ky) * 6 + (ox + kx);
            int gg = (k0 & 63) >> 3;
            int key = (pos2 + (spar << 2)) & 7;
            aoff[ks] = pos2 * 64 + ((gg ^ key) << 3);
        }
    }
    const int Gl = h * 8 + wave * 2 + (col >> 3);

    for (int c = 0; c < 8; ++c) {
        // stage 8 samples, verbatim linear copy (48 shorts/thread)
        const unsigned short* s2 = c2q + (size_t)(Q0 + c * 8) * 1536 + tid * 48;
        #pragma unroll
        for (int i = 0; i < 6; ++i)
            *(bf8*)&lds[tid * 48 + i * 8] = *(const bf8*)(s2 + i * 8);
        __syncthreads();

        f4 acc[4];
        #pragma unroll
        for (int mt = 0; mt < 4; ++mt) acc[mt] = (f4){0.f, 0.f, 0.f, 0.f};
        #pragma unroll
        for (int ks = 0; ks < 18; ++ks) {
            #pragma unroll
            for (int mt = 0; mt < 4; ++mt) {
                int sc = mt * 2 + (col >> 3);
                bf8 a = *(const bf8*)&lds[sc * 1536 + aoff[ks]];
                acc[mt] = MFMA(a, Bf3[ks], acc[mt]);
            }
        }
        // epilogue -> c3out, pre-swizzled for stem_gru (key = srow & 15)
        #pragma unroll
        for (int mt = 0; mt < 4; ++mt) {
            #pragma unroll
            for (int r = 0; r < 4; ++r) {
                int m = quad * 4 + r;
                int sc = mt * 2 + (m >> 3), opos = m & 7;
                int srow = sbase + Q0 + c * 8 + sc;
                c3[(size_t)srow * 1024 + opos * 128 + ((Gl ^ (srow & 15)) << 3) + (col & 7)]
                    = f2bf(lrelu(acc[mt][r]));
            }
        }
        __syncthreads();
    }
}

// ---- K3: stem GEMM + GRU + fc --------------------------------------------
// 1024 wgs, M=64 samples/wg. LDS: FUSED [0,12288) | A-dbuf [12288,28672).
__global__ __launch_bounds__(256, 2) void stem_gru(
    const unsigned short* __restrict__ ws, const float* __restrict__ v,
    const float* __restrict__ hx, const float* __restrict__ bvp,
    const float* __restrict__ bih, const float* __restrict__ bhh,
    const float* __restrict__ wfc, float* __restrict__ out)
{
    __shared__ __align__(16) unsigned short lds[28672];
    const int tid = threadIdx.x;
    const int wave = tid >> 6, lane = tid & 63;
    const int col = lane & 15, quad = lane >> 4;
    const int S0 = blockIdx.x * 64;
    const unsigned short* c3 = ws + C3_OFF;
    const unsigned short* wstem = ws + WSTEM_OFF;

    // ============ phase A: stem GEMM, K=1056 (v_proj fused as K-tail) ======
    f4 acc[4][3];
    #pragma unroll
    for (int mt = 0; mt < 4; ++mt)
        #pragma unroll
        for (int t = 0; t < 3; ++t) acc[mt][t] = (f4){0.f, 0.f, 0.f, 0.f};

    const int sm = tid >> 2, sq = tid & 3;
    const unsigned short* asrc = c3 + (size_t)(S0 + sm) * 1024 + sq * 32;

    #pragma unroll
    for (int i = 0; i < 4; ++i)
        *(bf8*)&lds[12288 + sm * 128 + sq * 32 + i * 8] = *(const bf8*)(asrc + i * 8);
    __syncthreads();

    for (int kc = 0; kc < 8; ++kc) {
        bf8 nx[4];
        if (kc < 7) {
            const unsigned short* s2 = asrc + (kc + 1) * 128;
            #pragma unroll
            for (int i = 0; i < 4; ++i) nx[i] = *(const bf8*)(s2 + i * 8);
        }
        int abase = 12288 + (kc & 1) * 8192;
        #pragma unroll
        for (int ks = 0; ks < 4; ++ks) {
            int kl = ks * 32 + quad * 8;
            int kk = kc * 128 + kl;
            bf8 b0 = *(const bf8*)(wstem + (wave * 48 + col) * 1056 + kk);
            bf8 b1 = *(const bf8*)(wstem + (wave * 48 + 16 + col) * 1056 + kk);
            bf8 b2 = *(const bf8*)(wstem + (wave * 48 + 32 + col) * 1056 + kk);
            #pragma unroll
            for (int mt = 0; mt < 4; ++mt) {
                int m = mt * 16 + col;
                bf8 a = *(const bf8*)&lds[abase + m * 128 + (kl ^ ((m & 15) << 3))];
                acc[mt][0] = MFMA(a, b0, acc[mt][0]);
                acc[mt][1] = MFMA(a, b1, acc[mt][1]);
                acc[mt][2] = MFMA(a, b2, acc[mt][2]);
            }
        }
        if (kc < 7) {
            int wb = 12288 + ((kc + 1) & 1) * 8192;
            #pragma unroll
            for (int i = 0; i < 4; ++i)
                *(bf8*)&lds[wb + sm * 128 + sq * 32 + i * 8] = nx[i];
        }
        __syncthreads();
    }

    // K-tail: v (9 cols, zero-padded to 32) into buf0
    if (tid < 64) {
        int m = tid;
        const float* vp = v + (size_t)(S0 + m) * 9;
        __align__(16) unsigned short tmp[32];
        #pragma unroll
        for (int i = 0; i < 9; ++i) tmp[i] = f2bf(vp[i]);
        #pragma unroll
        for (int i = 9; i < 32; ++i) tmp[i] = 0;
        #pragma unroll
        for (int gg = 0; gg < 4; ++gg) {
            int gp = gg ^ (m & 15);
            *(bf8*)&lds[12288 + m * 128 + gp * 8] = *(bf8*)&tmp[gg * 8];
        }
    }
    __syncthreads();
    {
        int kl = quad * 8;
        bf8 b0 = *(const bf8*)(wstem + (wave * 48 + col) * 1056 + 1024 + kl);
        bf8 b1 = *(const bf8*)(wstem + (wave * 48 + 16 + col) * 1056 + 1024 + kl);
        bf8 b2 = *(const bf8*)(wstem + (wave * 48 + 32 + col) * 1056 + 1024 + kl);
        #pragma unroll
        for (int mt = 0; mt < 4; ++mt) {
            int m = mt * 16 + col;
            bf8 a = *(const bf8*)&lds[12288 + m * 128 + (kl ^ ((m & 15) << 3))];
            acc[mt][0] = MFMA(a, b0, acc[mt][0]);
            acc[mt][1] = MFMA(a, b1, acc[mt][1]);
            acc[mt][2] = MFMA(a, b2, acc[mt][2]);
        }
    }

    // epilogue: + bias, lrelu -> FUSED
    #pragma unroll
    for (int t = 0; t < 3; ++t) {
        int n = wave * 48 + t * 16 + col;
        float bb = bvp[n];
        #pragma unroll
        for (int mt = 0; mt < 4; ++mt)
            #pragma unroll
            for (int r = 0; r < 4; ++r) {
                int m = mt * 16 + quad * 4 + r;
                lds[m * 192 + (n ^ ((m & 7) << 3))] = f2bf(lrelu(acc[mt][t][r] + bb));
            }
    }
    __syncthreads();

    // ============ phase B: GRU ============================================
    {
        int m = tid >> 2, qq = tid & 3;
        const float* hp = hx + (size_t)(S0 + m) * 192 + qq * 48;
        #pragma unroll
        for (int i = 0; i < 6; ++i) {
            f4 d = *(const f4*)(hp + i * 8 + 0);
            f4 d2 = *(const f4*)(hp + i * 8 + 4);
            __align__(16) unsigned short tmp[8];
            #pragma unroll
            for (int u = 0; u < 4; ++u) { tmp[u] = f2bf(d[u]); tmp[4 + u] = f2bf(d2[u]); }
            int gg = qq * 6 + i, gp = gg ^ (m & 7);
            *(bf8*)&lds[12288 + m * 192 + gp * 8] = *(bf8*)tmp;
        }
    }
    __syncthreads();

    #pragma unroll
    for (int t = 0; t < 3; ++t) {
        int j0 = (wave * 3 + t) * 16;
        int j = j0 + col;
        const unsigned short* pih = ws + WIH_OFF + j * 192;
        const unsigned short* phh = ws + WHH_OFF + j * 192;
        f4 g0[4], g1[4], g2[4], g3[4], g4[4], g5[4];
        #pragma unroll
        for (int mt = 0; mt < 4; ++mt) {
            g0[mt] = (f4){0.f,0.f,0.f,0.f}; g1[mt] = g0[mt]; g2[mt] = g0[mt];
            g3[mt] = g0[mt]; g4[mt] = g0[mt]; g5[mt] = g0[mt];
        }
        #pragma unroll
        for (int ks = 0; ks < 6; ++ks) {
            int k0 = ks * 32 + quad * 8;
            bf8 bir = *(const bf8*)(pih + k0);
            bf8 bhr = *(const bf8*)(phh + k0);
            bf8 biz = *(const bf8*)(pih + 36864 + k0);
            bf8 bhz = *(const bf8*)(phh + 36864 + k0);
            bf8 bin = *(const bf8*)(pih + 73728 + k0);
            bf8 bhn = *(const bf8*)(phh + 73728 + k0);
            #pragma unroll
            for (int mt = 0; mt < 4; ++mt) {
                int m = mt * 16 + col;
                int off = m * 192 + (k0 ^ ((m & 7) << 3));
                bf8 aF = *(const bf8*)&lds[off];
                bf8 aH = *(const bf8*)&lds[12288 + off];
                g0[mt] = MFMA(aF, bir, g0[mt]);
                g1[mt] = MFMA(aH, bhr, g1[mt]);
                g2[mt] = MFMA(aF, biz, g2[mt]);
                g3[mt] = MFMA(aH, bhz, g3[mt]);
                g4[mt] = MFMA(aF, bin, g4[mt]);
                g5[mt] = MFMA(aH, bhn, g5[mt]);
            }
        }
        float b_ir = bih[j], b_iz = bih[192 + j], b_in = bih[384 + j];
        float b_hr = bhh[j], b_hz = bhh[192 + j], b_hn = bhh[384 + j];
        #pragma unroll
        for (int mt = 0; mt < 4; ++mt)
            #pragma unroll
            for (int r = 0; r < 4; ++r) {
                int s = mt * 16 + quad * 4 + r;
                float rg = sigm(g0[mt][r] + b_ir + g1[mt][r] + b_hr);
                float zg = sigm(g2[mt][r] + b_iz + g3[mt][r] + b_hz);
                float ng = tanh_(g4[mt][r] + b_in + rg * (g5[mt][r] + b_hn));
                float hxv = hx[(size_t)(S0 + s) * 192 + j];
                float hnew = (1.f - zg) * ng + zg * hxv;
                out[65536 * 4 + (size_t)(S0 + s) * 192 + j] = hnew;
            }
    }
    __syncthreads();   // drain hnew stores (vmcnt(0) before barrier)

    // fc head: thread (s = tid&63, a = tid>>6), re-reads hnew from out (L2-hot)
    {
        int s = tid & 63, a = tid >> 6;
        const float* hp = out + 65536 * 4 + (size_t)(S0 + s) * 192;
        const float* wf = wfc + a * 192;
        float sum = 0.f;
        #pragma unroll 4
        for (int jj = 0; jj < 48; ++jj) {
            f4 hv = *(const f4*)(hp + jj * 4);
            f4 wv = *(const f4*)(wf + jj * 4);
            #pragma unroll
            for (int u = 0; u < 4; ++u) sum += lrelu(hv[u]) * wv[u];
        }
        out[(size_t)(S0 + s) * 4 + a] = sum;
    }
}

// ---------------------------------------------------------------------------
extern "C" void kernel_launch(void* const* d_in, const int* in_sizes, int n_in,
                              void* d_out, int out_size, void* d_ws, size_t ws_size,
                              hipStream_t stream) {
    const float* x     = (const float*)d_in[0];
    const float* v     = (const float*)d_in[1];
    const float* hx    = (const float*)d_in[2];
    const float* w1    = (const float*)d_in[3];
    const float* w2    = (const float*)d_in[4];
    const float* w3    = (const float*)d_in[5];
    const float* wstem = (const float*)d_in[6];
    const float* wvp   = (const float*)d_in[7];
    const float* bvp   = (const float*)d_in[8];
    const float* wih   = (const float*)d_in[9];
    const float* whh   = (const float*)d_in[10];
    const float* bih   = (const float*)d_in[11];
    const float* bhh   = (const float*)d_in[12];
    const float* wfc   = (const float*)d_in[13];
    unsigned short* wsp = (unsigned short*)d_ws;
    unsigned short* c3  = wsp + C3_OFF;
    unsigned short* c2q = wsp + C2Q_OFF;

    prep_weights<<<2016, 256, 0, stream>>>(w2, w3, wstem, wvp, wih, whh, wsp);
    for (int q = 0; q < 4; ++q) {
        conv12<<<512, 256, 0, stream>>>(x, w1, wsp, c2q, q * 16384);
        conv3k<<<512, 256, 0, stream>>>(wsp, c2q, c3, q * 16384);
    }
    stem_gru<<<1024, 256, 0, stream>>>(wsp, v, hx, bvp, bih, bhh, wfc, (float*)d_out);
}